// Round 10
// baseline (643.086 us; speedup 1.0000x reference)
//
#include <hip/hip_runtime.h>

typedef __attribute__((ext_vector_type(8))) short short8;
typedef __attribute__((ext_vector_type(4))) float f32x4;
typedef unsigned short u16;
typedef unsigned int u32;

// round-to-nearest-even f32 -> bf16
__device__ __forceinline__ u16 f2bf(float f){
  union { float f; u32 u; } v; v.f = f;
  u32 u = v.u;
  u32 r = (u + 0x7FFFu + ((u >> 16) & 1u)) >> 16;
  return (u16)r;
}

// pack two f32 -> bf16x2 (RNE), S0 in low half
__device__ __forceinline__ u32 cvtpk(float a, float b){
  u32 r;
  asm("v_cvt_pk_bf16_f32 %0, %1, %2" : "=v"(r) : "v"(a), "v"(b));
  return r;
}

// XOR swizzle on byte-in-row (bits 4..6) to break power-of-2 row strides
__device__ __forceinline__ int swz(int row, int cb){ return cb ^ ((row & 7) << 4); }

// ===========================================================================
// K0: weights -> FRAGMENT-MAJOR bf16 layouts (r7-verified).
// wqf chunks [bn:12][kt:8][nsub:8][ks:2][l:64] : 16B chunk (l) holds
//   wqkv^T[e = bn*128+nsub*16+(l&15)][k = kt*64+ks*32+(l>>4)*8 .. +8)
// wpf chunks [cb:8][hh:8][n:4][ks:2][l:64] :
//   wproj^T[e = cb*64+n*16+(l&15)][k = hh*64+ks*32+(l>>4)*8 .. +8)
// ===========================================================================
__global__ void convert_weights_frag(const float* __restrict__ wqkv,
                                     const float* __restrict__ wproj,
                                     u16* __restrict__ wqf,
                                     u16* __restrict__ wpf){
  int c = blockIdx.x * 256 + threadIdx.x;    // 131072 chunks total
  union { u16 u[8]; uint4 v; } t;
  if (c < 98304){
    int bn = c >> 13;
    int r  = c & 8191;
    int kt = r >> 10;
    int q  = r & 1023;
    int nsub = q >> 7;
    int ks = (q >> 6) & 1;
    int l  = q & 63;
    int e  = bn*128 + nsub*16 + (l & 15);
    int k0 = kt*64 + ks*32 + (l >> 4)*8;
    #pragma unroll
    for (int i = 0; i < 8; ++i) t.u[i] = f2bf(wqkv[(long)(k0 + i) * 1536 + e]);
    *reinterpret_cast<uint4*>(wqf + (long)c * 8) = t.v;
  } else {
    int c2 = c - 98304;
    int cb = c2 >> 12;
    int r  = c2 & 4095;
    int hh = r >> 9;
    int q  = r & 511;
    int n  = q >> 7;
    int ks = (q >> 6) & 1;
    int l  = q & 63;
    int e  = cb*64 + n*16 + (l & 15);
    int k0 = hh*64 + ks*32 + (l >> 4)*8;
    #pragma unroll
    for (int i = 0; i < 8; ++i) t.u[i] = f2bf(wproj[(long)(k0 + i) * 512 + e]);
    *reinterpret_cast<uint4*>(wpf + (long)c2 * 8) = t.v;
  }
}

// ===========================================================================
// K1: FULLY FUSED. One block = one 64-token window, 8 waves, wave = head.
// Phases per wave (no inter-wave coupling until proj):
//   0. block: stage x window f32 -> bf16 swizzled LDS (64 KB), 1 barrier
//   1. Q = Xw @ Wq_h  (B frags direct from wqf)  -> slot [tok][d] -> qa regs
//   2. K = Xw @ Wk_h  -> slot [tok][d] -> kb regs
//   3. V = Xw @ Wv_h  -> slot as V^T [d][tok]
//   4. S^T = mfma(K,Q); in-register softmax; P via cvtpk+shfl; O = P V
//   5. O -> slot; __syncthreads; proj: 64-col slice over all 8 heads' O
// ===========================================================================
__global__ __launch_bounds__(512, 2) void fused_all(
    const float* __restrict__ x,
    const u16*  __restrict__ wqf,
    const float* __restrict__ bqkv,
    const u16*  __restrict__ wpf,
    const float* __restrict__ bproj,
    float* __restrict__ out)
{
  __shared__ u16 xw[64 * 512];     // 64 KB, 1024B rows, swizzled
  __shared__ u16 slots[8][4096];   // 8 KB per wave: Q,K,V^T,O time-shared

  const int tid = threadIdx.x;
  const int l = tid & 63, w = tid >> 6;
  const int g = l >> 4,  ln = l & 15;
  const int gh = g >> 1, gl = g & 1;
  const long tokb = (long)blockIdx.x * 64;
  const int h = w;
  u16* slot = slots[w];

  // ---- phase 0: stage x window (coalesced float4, cvt_pk, swizzled) ----
  {
    const float4* xv = reinterpret_cast<const float4*>(x + tokb * 512);
    #pragma unroll
    for (int i = 0; i < 16; ++i){
      int idx = i * 512 + tid;          // float4 index in 64x128
      int row = idx >> 7, c4 = idx & 127;
      float4 v = xv[idx];
      uint2 pk;
      pk.x = cvtpk(v.x, v.y);
      pk.y = cvtpk(v.z, v.w);
      *reinterpret_cast<uint2*>(reinterpret_cast<char*>(xw) + row*1024 + swz(row, c4*8)) = pk;
    }
  }
  __syncthreads();

  // ---- per-head QKV GEMM helper: acc = Xw(64x512) @ W_s_h(512x64) ----
  f32x4 acc[4][4];
  auto gemmQKV = [&](int s){
    #pragma unroll
    for (int m = 0; m < 4; ++m)
      #pragma unroll
      for (int n = 0; n < 4; ++n) acc[m][n] = (f32x4){0.f,0.f,0.f,0.f};
    const u16* bb = wqf + (long)(s*4 + (h >> 1)) * 65536;
    const int nsb = (h & 1) * 4;
    #pragma unroll
    for (int kk = 0; kk < 16; ++kk){
      short8 bf[4], af[4];
      #pragma unroll
      for (int n = 0; n < 4; ++n)
        bf[n] = *reinterpret_cast<const short8*>(
            bb + ((((kk>>1)*8 + nsb + n)*2 + (kk & 1))*64 + l)*8);
      #pragma unroll
      for (int m = 0; m < 4; ++m){
        int r = m*16 + ln;
        af[m] = *reinterpret_cast<const short8*>(
            reinterpret_cast<const char*>(xw) + r*1024 + swz(r, (kk*32 + g*8)*2));
      }
      __builtin_amdgcn_s_setprio(1);
      #pragma unroll
      for (int m = 0; m < 4; ++m)
        #pragma unroll
        for (int n = 0; n < 4; ++n)
          acc[m][n] = __builtin_amdgcn_mfma_f32_16x16x32_bf16(af[m], bf[n], acc[m][n], 0, 0, 0);
      __builtin_amdgcn_s_setprio(0);
    }
  };

  // write acc (C-layout) as [tok][d] rows into slot, with bias
  auto accToRows = [&](int boff){
    #pragma unroll
    for (int n = 0; n < 4; ++n){
      int d = n*16 + ln;
      float bias = bqkv[boff + h*64 + d];
      #pragma unroll
      for (int m = 0; m < 4; ++m)
        #pragma unroll
        for (int r = 0; r < 4; ++r){
          int t = m*16 + g*4 + r;
          *reinterpret_cast<u16*>(reinterpret_cast<char*>(slot) + t*128 + swz(t, d*2)) =
              f2bf(acc[m][n][r] + bias);
        }
    }
  };

  short8 qa[4][2], kb[4][2];

  // ---- phase 1: Q ----
  gemmQKV(0);
  accToRows(0);
  asm volatile("s_waitcnt lgkmcnt(0)" ::: "memory");
  #pragma unroll
  for (int j = 0; j < 4; ++j){
    int r = j*16 + ln;
    #pragma unroll
    for (int ks = 0; ks < 2; ++ks)
      qa[j][ks] = *reinterpret_cast<const short8*>(
          reinterpret_cast<const char*>(slot) + r*128 + swz(r, (ks*32 + g*8)*2));
  }
  asm volatile("s_waitcnt lgkmcnt(0)" ::: "memory");

  // ---- phase 2: K ----
  gemmQKV(1);
  accToRows(512);
  asm volatile("s_waitcnt lgkmcnt(0)" ::: "memory");
  #pragma unroll
  for (int mk = 0; mk < 4; ++mk){
    int r = mk*16 + ln;
    #pragma unroll
    for (int ks = 0; ks < 2; ++ks)
      kb[mk][ks] = *reinterpret_cast<const short8*>(
          reinterpret_cast<const char*>(slot) + r*128 + swz(r, (ks*32 + g*8)*2));
  }
  asm volatile("s_waitcnt lgkmcnt(0)" ::: "memory");

  // ---- phase 3: V -> V^T in slot ----
  gemmQKV(2);
  #pragma unroll
  for (int n = 0; n < 4; ++n){
    int d = n*16 + ln;
    float bias = bqkv[1024 + h*64 + d];
    #pragma unroll
    for (int m = 0; m < 4; ++m){
      uint2 pk;
      pk.x = cvtpk(acc[m][n][0] + bias, acc[m][n][1] + bias);
      pk.y = cvtpk(acc[m][n][2] + bias, acc[m][n][3] + bias);
      *reinterpret_cast<uint2*>(reinterpret_cast<char*>(slot) + d*128 + swz(d, (m*16 + g*4)*2)) = pk;
    }
  }
  asm volatile("s_waitcnt lgkmcnt(0)" ::: "memory");

  // ---- phase 4: S^T = mfma(K, Q); softmax; P; O = P V ----
  f32x4 st[4][4];
  #pragma unroll
  for (int mk = 0; mk < 4; ++mk)
    #pragma unroll
    for (int j = 0; j < 4; ++j) st[mk][j] = (f32x4){0.f,0.f,0.f,0.f};
  __builtin_amdgcn_s_setprio(1);
  #pragma unroll
  for (int mk = 0; mk < 4; ++mk)
    #pragma unroll
    for (int j = 0; j < 4; ++j)
      #pragma unroll
      for (int ks = 0; ks < 2; ++ks)
        st[mk][j] = __builtin_amdgcn_mfma_f32_16x16x32_bf16(kb[mk][ks], qa[j][ks], st[mk][j], 0, 0, 0);
  __builtin_amdgcn_s_setprio(0);

  u32 warr[4][4][2];
  #pragma unroll
  for (int j = 0; j < 4; ++j){
    float mx = -3.4e38f;
    #pragma unroll
    for (int mk = 0; mk < 4; ++mk)
      #pragma unroll
      for (int r = 0; r < 4; ++r) mx = fmaxf(mx, st[mk][j][r]);
    mx = fmaxf(mx, __shfl_xor(mx, 16, 64));
    mx = fmaxf(mx, __shfl_xor(mx, 32, 64));
    float s = 0.f;
    #pragma unroll
    for (int mk = 0; mk < 4; ++mk)
      #pragma unroll
      for (int r = 0; r < 4; ++r){
        float p = __expf((st[mk][j][r] - mx) * 0.125f);
        st[mk][j][r] = p; s += p;
      }
    s += __shfl_xor(s, 16, 64);
    s += __shfl_xor(s, 32, 64);
    float inv = 1.f / s;
    #pragma unroll
    for (int mk = 0; mk < 4; ++mk){
      warr[mk][j][0] = cvtpk(st[mk][j][0]*inv, st[mk][j][1]*inv);
      warr[mk][j][1] = cvtpk(st[mk][j][2]*inv, st[mk][j][3]*inv);
    }
  }

  f32x4 oacc[4][4];
  #pragma unroll
  for (int m = 0; m < 4; ++m)
    #pragma unroll
    for (int n = 0; n < 4; ++n) oacc[m][n] = (f32x4){0.f,0.f,0.f,0.f};
  const int lnA = ln + 32*gl;
  #pragma unroll
  for (int ks = 0; ks < 2; ++ks){
    short8 vb[4];
    #pragma unroll
    for (int n = 0; n < 4; ++n){
      int row = n*16 + ln;
      vb[n] = *reinterpret_cast<const short8*>(
          reinterpret_cast<const char*>(slot) + row*128 + swz(row, (ks*32 + g*8)*2));
    }
    __builtin_amdgcn_s_setprio(1);
    #pragma unroll
    for (int m = 0; m < 4; ++m){
      u32 c0a = warr[2*ks  ][m][0], c0b = warr[2*ks  ][m][1];
      u32 c1a = warr[2*ks+1][m][0], c1b = warr[2*ks+1][m][1];
      u32 s0a = (u32)__shfl((int)c0a, lnA, 64);
      u32 s1a = (u32)__shfl((int)c1a, lnA, 64);
      u32 s0b = (u32)__shfl((int)c0b, lnA, 64);
      u32 s1b = (u32)__shfl((int)c1b, lnA, 64);
      u32 t0a = (u32)__shfl((int)c0a, lnA+16, 64);
      u32 t1a = (u32)__shfl((int)c1a, lnA+16, 64);
      u32 t0b = (u32)__shfl((int)c0b, lnA+16, 64);
      u32 t1b = (u32)__shfl((int)c1b, lnA+16, 64);
      union { u32 u[4]; short8 v; } pf;
      pf.u[0] = gh ? s1a : s0a;
      pf.u[1] = gh ? s1b : s0b;
      pf.u[2] = gh ? t1a : t0a;
      pf.u[3] = gh ? t1b : t0b;
      #pragma unroll
      for (int n = 0; n < 4; ++n)
        oacc[m][n] = __builtin_amdgcn_mfma_f32_16x16x32_bf16(pf.v, vb[n], oacc[m][n], 0, 0, 0);
    }
    __builtin_amdgcn_s_setprio(0);
  }

  // ---- O -> slot (overwrite V^T; vb reads complete by data dep) ----
  #pragma unroll
  for (int m = 0; m < 4; ++m)
    #pragma unroll
    for (int n = 0; n < 4; ++n){
      int d = n*16 + ln;
      #pragma unroll
      for (int r = 0; r < 4; ++r){
        int t = m*16 + g*4 + r;
        *reinterpret_cast<u16*>(reinterpret_cast<char*>(slot) + t*128 + swz(t, d*2)) =
            f2bf(oacc[m][n][r]);
      }
    }

  __syncthreads();

  // ---- phase 5: proj (cols w*64..w*64+64 over all 8 heads' O) ----
  f32x4 pacc[4][4];
  #pragma unroll
  for (int m = 0; m < 4; ++m)
    #pragma unroll
    for (int n = 0; n < 4; ++n) pacc[m][n] = (f32x4){0.f,0.f,0.f,0.f};

  for (int hh = 0; hh < 8; ++hh){
    const char* obuf = (const char*)slots[hh];
    #pragma unroll
    for (int ks = 0; ks < 2; ++ks){
      short8 a[4], b[4];
      #pragma unroll
      for (int m = 0; m < 4; ++m){
        int row = m*16 + ln;
        a[m] = *reinterpret_cast<const short8*>(obuf + row*128 + swz(row, (ks*32 + g*8)*2));
      }
      #pragma unroll
      for (int n = 0; n < 4; ++n)
        b[n] = *reinterpret_cast<const short8*>(
            wpf + ((((long)w*8 + hh)*4 + n)*2 + ks)*512 + (long)l*8);
      __builtin_amdgcn_s_setprio(1);
      #pragma unroll
      for (int m = 0; m < 4; ++m)
        #pragma unroll
        for (int n = 0; n < 4; ++n)
          pacc[m][n] = __builtin_amdgcn_mfma_f32_16x16x32_bf16(a[m], b[n], pacc[m][n], 0, 0, 0);
      __builtin_amdgcn_s_setprio(0);
    }
  }

  #pragma unroll
  for (int n = 0; n < 4; ++n){
    int col = w*64 + n*16 + ln;
    float bias = bproj[col];
    #pragma unroll
    for (int m = 0; m < 4; ++m){
      #pragma unroll
      for (int r = 0; r < 4; ++r){
        int t = m*16 + g*4 + r;
        out[(tokb + t) * 512 + col] = pacc[m][n][r] + bias;
      }
    }
  }
}

// ===========================================================================
// Fallback (round-1 fused kernel) for small ws_size
// ===========================================================================
__global__ void convert_weights(const float* __restrict__ wqkv,
                                const float* __restrict__ wproj,
                                u16* __restrict__ wqkvt,
                                u16* __restrict__ wprojt){
  int tid = blockIdx.x * 256 + threadIdx.x;
  union { u16 u[8]; uint4 v; } tmp;
  if (tid < 1536 * 64){
    int e  = tid >> 6;
    int kc = (tid & 63) << 3;
    #pragma unroll
    for (int i = 0; i < 8; ++i) tmp.u[i] = f2bf(wqkv[(long)(kc + i) * 1536 + e]);
    *reinterpret_cast<uint4*>(wqkvt + (long)e * 512 + kc) = tmp.v;
  } else {
    int t2 = tid - 1536 * 64;
    int c  = t2 >> 6;
    int kc = (t2 & 63) << 3;
    #pragma unroll
    for (int i = 0; i < 8; ++i) tmp.u[i] = f2bf(wproj[(long)(kc + i) * 512 + c]);
    *reinterpret_cast<uint4*>(wprojt + (long)c * 512 + kc) = tmp.v;
  }
}

__global__ __launch_bounds__(512, 2) void fused_winattn(
    const float* __restrict__ x,
    const u16*  __restrict__ wqkvt,
    const float* __restrict__ bqkv,
    const u16*  __restrict__ wprojt,
    const float* __restrict__ bproj,
    float* __restrict__ out)
{
  __shared__ u16 lds_x[64 * 512];
  __shared__ u16 lds_q[64 * 64];
  __shared__ u16 lds_k[64 * 64];
  __shared__ u16 lds_vt[64 * 64];
  __shared__ u16 lds_p[64 * 64];

  const int tid = threadIdx.x;
  const int l   = tid & 63;
  const int w   = tid >> 6;
  const int g   = l >> 4;
  const int ln  = l & 15;
  const long tokbase = (long)blockIdx.x * 64;

  {
    const float4* xv = reinterpret_cast<const float4*>(x + tokbase * 512);
    #pragma unroll
    for (int j = 0; j < 16; ++j){
      int i   = j * 512 + tid;
      int row = i >> 7;
      int c4  = i & 127;
      float4 v = xv[i];
      uint2 pk;
      pk.x = (u32)f2bf(v.x) | ((u32)f2bf(v.y) << 16);
      pk.y = (u32)f2bf(v.z) | ((u32)f2bf(v.w) << 16);
      int byte = row * 1024 + swz(row, c4 * 8);
      *reinterpret_cast<uint2*>(reinterpret_cast<char*>(lds_x) + byte) = pk;
    }
  }

  f32x4 oacc[4][4];
  #pragma unroll
  for (int m = 0; m < 4; ++m)
    #pragma unroll
    for (int n = 0; n < 4; ++n) oacc[m][n] = (f32x4){0.f, 0.f, 0.f, 0.f};

  const int mw   = w & 3;
  const int half = w >> 2;

  __syncthreads();

  for (int h = 0; h < 8; ++h){
    f32x4 qacc[6];
    #pragma unroll
    for (int j = 0; j < 6; ++j) qacc[j] = (f32x4){0.f, 0.f, 0.f, 0.f};
    int ebase[6];
    #pragma unroll
    for (int j = 0; j < 6; ++j){
      int nt = half * 6 + j;
      int sec = nt >> 2;
      ebase[j] = sec * 512 + h * 64 + (nt & 3) * 16;
    }
    const int arow = mw * 16 + ln;
    #pragma unroll
    for (int ks = 0; ks < 16; ++ks){
      short8 a = *reinterpret_cast<const short8*>(
          reinterpret_cast<const char*>(lds_x) + arow * 1024 + swz(arow, (ks * 32 + g * 8) * 2));
      #pragma unroll
      for (int j = 0; j < 6; ++j){
        short8 b = *reinterpret_cast<const short8*>(
            wqkvt + (long)(ebase[j] + ln) * 512 + ks * 32 + g * 8);
        qacc[j] = __builtin_amdgcn_mfma_f32_16x16x32_bf16(a, b, qacc[j], 0, 0, 0);
      }
    }
    #pragma unroll
    for (int j = 0; j < 6; ++j){
      int nt  = half * 6 + j;
      int sec = nt >> 2;
      float bias = bqkv[ebase[j] + ln];
      if (sec < 2){
        u16* dst = (sec == 0) ? lds_q : lds_k;
        int c = (nt & 3) * 16 + ln;
        #pragma unroll
        for (int r = 0; r < 4; ++r){
          int t = mw * 16 + g * 4 + r;
          int byte = t * 128 + swz(t, c * 2);
          *reinterpret_cast<u16*>(reinterpret_cast<char*>(dst) + byte) = f2bf(qacc[j][r] + bias);
        }
      } else {
        int d  = (nt & 3) * 16 + ln;
        int t0 = mw * 16 + g * 4;
        uint2 pk;
        pk.x = (u32)f2bf(qacc[j][0] + bias) | ((u32)f2bf(qacc[j][1] + bias) << 16);
        pk.y = (u32)f2bf(qacc[j][2] + bias) | ((u32)f2bf(qacc[j][3] + bias) << 16);
        int byte = d * 128 + swz(d, t0 * 2);
        *reinterpret_cast<uint2*>(reinterpret_cast<char*>(lds_vt) + byte) = pk;
      }
    }
    __syncthreads();

    if (w < 4){
      f32x4 sacc[4];
      #pragma unroll
      for (int jt = 0; jt < 4; ++jt) sacc[jt] = (f32x4){0.f, 0.f, 0.f, 0.f};
      #pragma unroll
      for (int ks = 0; ks < 2; ++ks){
        int qrow = w * 16 + ln;
        short8 a = *reinterpret_cast<const short8*>(
            reinterpret_cast<const char*>(lds_q) + qrow * 128 + swz(qrow, (ks * 32 + g * 8) * 2));
        #pragma unroll
        for (int jt = 0; jt < 4; ++jt){
          int krow = jt * 16 + ln;
          short8 b = *reinterpret_cast<const short8*>(
              reinterpret_cast<const char*>(lds_k) + krow * 128 + swz(krow, (ks * 32 + g * 8) * 2));
          sacc[jt] = __builtin_amdgcn_mfma_f32_16x16x32_bf16(a, b, sacc[jt], 0, 0, 0);
        }
      }
      #pragma unroll
      for (int r = 0; r < 4; ++r){
        float mx = fmaxf(fmaxf(sacc[0][r], sacc[1][r]), fmaxf(sacc[2][r], sacc[3][r]));
        mx = fmaxf(mx, __shfl_xor(mx, 1, 64));
        mx = fmaxf(mx, __shfl_xor(mx, 2, 64));
        mx = fmaxf(mx, __shfl_xor(mx, 4, 64));
        mx = fmaxf(mx, __shfl_xor(mx, 8, 64));
        float p[4], s = 0.f;
        #pragma unroll
        for (int jt = 0; jt < 4; ++jt){
          p[jt] = __expf((sacc[jt][r] - mx) * 0.125f);
          s += p[jt];
        }
        s += __shfl_xor(s, 1, 64);
        s += __shfl_xor(s, 2, 64);
        s += __shfl_xor(s, 4, 64);
        s += __shfl_xor(s, 8, 64);
        float inv = 1.f / s;
        int i = w * 16 + g * 4 + r;
        #pragma unroll
        for (int jt = 0; jt < 4; ++jt){
          int c = jt * 16 + ln;
          int byte = i * 128 + swz(i, c * 2);
          *reinterpret_cast<u16*>(reinterpret_cast<char*>(lds_p) + byte) = f2bf(p[jt] * inv);
        }
      }
    }
    __syncthreads();

    {
      int mc  = w & 3;
      int nc0 = (w >> 2) * 2;
      f32x4 oc[2];
      oc[0] = (f32x4){0.f, 0.f, 0.f, 0.f};
      oc[1] = (f32x4){0.f, 0.f, 0.f, 0.f};
      #pragma unroll
      for (int ks = 0; ks < 2; ++ks){
        int prow = mc * 16 + ln;
        short8 a = *reinterpret_cast<const short8*>(
            reinterpret_cast<const char*>(lds_p) + prow * 128 + swz(prow, (ks * 32 + g * 8) * 2));
        #pragma unroll
        for (int jj = 0; jj < 2; ++jj){
          int vrow = (nc0 + jj) * 16 + ln;
          short8 b = *reinterpret_cast<const short8*>(
              reinterpret_cast<const char*>(lds_vt) + vrow * 128 + swz(vrow, (ks * 32 + g * 8) * 2));
          oc[jj] = __builtin_amdgcn_mfma_f32_16x16x32_bf16(a, b, oc[jj], 0, 0, 0);
        }
      }
      #pragma unroll
      for (int jj = 0; jj < 2; ++jj){
        int d = (nc0 + jj) * 16 + ln;
        #pragma unroll
        for (int r = 0; r < 4; ++r){
          int t = mc * 16 + g * 4 + r;
          int byte = t * 128 + swz(t, d * 2);
          *reinterpret_cast<u16*>(reinterpret_cast<char*>(lds_q) + byte) = f2bf(oc[jj][r]);
        }
      }
    }
    __syncthreads();

    #pragma unroll
    for (int ks = 0; ks < 2; ++ks){
      short8 a[4];
      #pragma unroll
      for (int m = 0; m < 4; ++m){
        int row = m * 16 + ln;
        a[m] = *reinterpret_cast<const short8*>(
            reinterpret_cast<const char*>(lds_q) + row * 128 + swz(row, (ks * 32 + g * 8) * 2));
      }
      #pragma unroll
      for (int nt = 0; nt < 4; ++nt){
        int e = w * 64 + nt * 16 + ln;
        short8 b = *reinterpret_cast<const short8*>(
            wprojt + (long)e * 512 + h * 64 + ks * 32 + g * 8);
        #pragma unroll
        for (int m = 0; m < 4; ++m)
          oacc[m][nt] = __builtin_amdgcn_mfma_f32_16x16x32_bf16(a[m], b, oacc[m][nt], 0, 0, 0);
      }
    }
    __syncthreads();
  }

  #pragma unroll
  for (int nt = 0; nt < 4; ++nt){
    int col = w * 64 + nt * 16 + ln;
    float bias = bproj[col];
    #pragma unroll
    for (int m = 0; m < 4; ++m){
      #pragma unroll
      for (int r = 0; r < 4; ++r){
        int t = m * 16 + g * 4 + r;
        out[(tokbase + t) * 512 + col] = oacc[m][nt][r] + bias;
      }
    }
  }
}

extern "C" void kernel_launch(void* const* d_in, const int* in_sizes, int n_in,
                              void* d_out, int out_size, void* d_ws, size_t ws_size,
                              hipStream_t stream) {
  const float* x     = (const float*)d_in[0];
  const float* wqkv  = (const float*)d_in[1];
  const float* bqkv  = (const float*)d_in[2];
  const float* wproj = (const float*)d_in[3];
  const float* bproj = (const float*)d_in[4];
  float* out = (float*)d_out;

  // wqf 1.5 MB + wpf 0.5 MB
  const size_t NEED = 2097152ULL;
  if (ws_size >= NEED){
    u16* wqf = (u16*)d_ws;
    u16* wpf = (u16*)((char*)d_ws + 1572864);
    convert_weights_frag<<<512, 256, 0, stream>>>(wqkv, wproj, wqf, wpf);
    fused_all<<<2048, 512, 0, stream>>>(x, wqf, bqkv, wpf, bproj, out);
  } else {
    u16* wqkvt  = (u16*)d_ws;
    u16* wprojt = wqkvt + 1536 * 512;
    convert_weights<<<512, 256, 0, stream>>>(wqkv, wproj, wqkvt, wprojt);
    fused_winattn<<<2048, 512, 0, stream>>>(x, wqkvt, bqkv, wprojt, bproj, out);
  }
}